// Round 1
// baseline (5446.929 us; speedup 1.0000x reference)
//
#include <hip/hip_runtime.h>
#include <math.h>

#define VOL 729000
#define SL  8100
#define RW  90

// 12 offset pairs (dz,dy,dx), already dilated (*2) and centered (-2..2)
__device__ __constant__ int c_o1[12][3] = {
  {0,0,-2},{0,-2,0},{0,-2,0},{0,0,2},{0,0,2},{2,0,0},{2,0,0},{2,0,0},{0,2,0},{0,2,0},{0,2,0},{0,2,0}
};
__device__ __constant__ int c_o2[12][3] = {
  {-2,0,0},{-2,0,0},{0,0,-2},{-2,0,0},{0,-2,0},{0,0,-2},{0,-2,0},{0,0,2},{-2,0,0},{0,0,-2},{0,0,2},{2,0,0}
};

__device__ __forceinline__ int clampi(int v, int lo, int hi){ return v<lo?lo:(v>hi?hi:v); }

// diff2: out[b][t][z][y][x] = (img[b][clamp(v+o1)] - img[b][clamp(v+o2)])^2
__global__ void diff2_kernel(const float* __restrict__ img, float* __restrict__ out) {
  int idx = blockIdx.x*256 + threadIdx.x;
  if (idx >= 2*12*VOL) return;
  int vox = idx % VOL;
  int ct  = idx / VOL;           // b*12 + t
  int t = ct % 12, b = ct / 12;
  int z = vox / SL; int r = vox % SL; int y = r / RW; int x = r % RW;
  const float* im = img + (size_t)b*VOL;
  int z1 = clampi(z + c_o1[t][0],0,89), y1 = clampi(y + c_o1[t][1],0,89), x1 = clampi(x + c_o1[t][2],0,89);
  int z2 = clampi(z + c_o2[t][0],0,89), y2 = clampi(y + c_o2[t][1],0,89), x2 = clampi(x + c_o2[t][2],0,89);
  float d = im[z1*SL+y1*RW+x1] - im[z2*SL+y2*RW+x2];
  out[idx] = d*d;
}

__global__ void boxz_kernel(const float* __restrict__ in, float* __restrict__ out) {
  int idx = blockIdx.x*256 + threadIdx.x;
  if (idx >= 2*12*VOL) return;
  int vox = idx % VOL; int bc = idx / VOL;
  int z = vox / SL; int r = vox % SL;
  const float* p = in + (size_t)bc*VOL + r;
  float s = 0.f;
  #pragma unroll
  for (int d=-2; d<=2; ++d) { int zc = clampi(z+d,0,89); s += p[(size_t)zc*SL]; }
  out[idx] = s;
}

__global__ void boxy_kernel(const float* __restrict__ in, float* __restrict__ out) {
  int idx = blockIdx.x*256 + threadIdx.x;
  if (idx >= 2*12*VOL) return;
  int vox = idx % VOL; int bc = idx / VOL;
  int z = vox / SL; int r = vox % SL; int y = r / RW; int x = r % RW;
  const float* p = in + (size_t)bc*VOL + (size_t)z*SL + x;
  float s = 0.f;
  #pragma unroll
  for (int d=-2; d<=2; ++d) { int yc = clampi(y+d,0,89); s += p[yc*RW]; }
  out[idx] = s;
}

// x box (fused /125), channel min, write pre = ssd - min, accumulate sum of per-voxel mv
__global__ void boxx_min_kernel(const float* __restrict__ in, float* __restrict__ outPre,
                                float* __restrict__ mvsum) {
  __shared__ float red;
  if (threadIdx.x == 0) red = 0.f;
  __syncthreads();
  int idx = blockIdx.x*256 + threadIdx.x;
  float mv = 0.f;
  if (idx < 2*VOL) {
    int b = idx / VOL; int vox = idx % VOL;
    int z = vox / SL; int r = vox % SL; int y = r / RW; int x = r % RW;
    const float* base = in + (size_t)b*12*VOL + (size_t)z*SL + (size_t)y*RW;
    float s[12]; float mn = 3.4e38f;
    #pragma unroll
    for (int c=0;c<12;++c) {
      const float* pc = base + (size_t)c*VOL;
      float t = 0.f;
      #pragma unroll
      for (int d=-2;d<=2;++d) { int xc = clampi(x+d,0,89); t += pc[xc]; }
      t *= (1.0f/125.0f);
      s[c] = t; mn = fminf(mn, t);
    }
    float* ob = outPre + (size_t)b*12*VOL + vox;
    #pragma unroll
    for (int c=0;c<12;++c) { float pre = s[c]-mn; ob[(size_t)c*VOL] = pre; mv += pre; }
    mv *= (1.0f/12.0f);
  }
  #pragma unroll
  for (int o=32;o;o>>=1) mv += __shfl_xor(mv, o);
  if ((threadIdx.x & 63)==0 && mv != 0.f) atomicAdd(&red, mv);
  __syncthreads();
  if (threadIdx.x==0) atomicAdd(mvsum, red);
}

// in-place: pre -> exp(-pre / clip(mean_c(pre), mm*1e-3, mm*1e3))
__global__ void finalize_kernel(float* __restrict__ pre, const float* __restrict__ mvsum) {
  int idx = blockIdx.x*256 + threadIdx.x;
  if (idx >= 2*VOL) return;
  int b = idx / VOL; int vox = idx % VOL;
  float* base = pre + (size_t)b*12*VOL + vox;
  float s[12]; float mv = 0.f;
  #pragma unroll
  for (int c=0;c<12;++c) { s[c] = base[(size_t)c*VOL]; mv += s[c]; }
  mv *= (1.0f/12.0f);
  float mm = *mvsum * (1.0f/1458000.0f);
  float mvc = fminf(fmaxf(mv, mm*0.001f), mm*1000.0f);
  float inv = 1.0f / mvc;
  #pragma unroll
  for (int c=0;c<12;++c) base[(size_t)c*VOL] = __expf(-s[c]*inv);
}

// pack moving volume -> [b][n][C] contiguous descriptors (reference (C,p,p,p) order)
template<int P>
__global__ void pack_kernel(const float* __restrict__ mind, float* __restrict__ out) {
  constexpr int NG = 90/P, N = NG*NG*NG, C = 12*P*P*P;
  int idx = blockIdx.x*256 + threadIdx.x;
  if (idx >= 2*N*C) return;
  int j = idx % C; int bn = idx / C;
  int n = bn % N; int b = bn / N;
  int c = j/(P*P*P); int r = j%(P*P*P); int dz = r/(P*P); int r2 = r%(P*P); int dy = r2/P; int dx = r2%P;
  int bz = n/(NG*NG); int rn = n%(NG*NG); int by = rn/NG; int bx = rn%NG;
  out[idx] = mind[((size_t)b*12 + c)*VOL + (size_t)(bz*P+dz)*SL + (size_t)(by*P+dy)*RW + (bx*P+dx)];
}

template<int C>
__global__ __launch_bounds__(64) void norm_kernel(const float* __restrict__ packed,
                                                  float* __restrict__ inv) {
  int pid = blockIdx.x;
  const float4* d = (const float4*)(packed + (size_t)pid*C);
  float ss = 0.f;
  for (int k=threadIdx.x; k<C/4; k+=64) { float4 v = d[k]; ss += v.x*v.x + v.y*v.y + v.z*v.z + v.w*v.w; }
  #pragma unroll
  for (int o=32;o;o>>=1) ss += __shfl_xor(ss, o);
  if (threadIdx.x==0) inv[pid] = 1.0f/fmaxf(sqrtf(ss), 1e-12f);
}

// one wave per (b,n): gather pa from mind_f volume into LDS, dot with neighborhood of packed moving
template<int P, int R>
__global__ __launch_bounds__(64) void loss_kernel(
    const float* __restrict__ mindF, const float* __restrict__ packedM,
    const float* __restrict__ invB, float* __restrict__ acc) {
  constexpr int NG = 90/P, N = NG*NG*NG, C = 12*P*P*P;
  __shared__ __align__(16) float pa[C];
  int blk = blockIdx.x;
  int b = blk / N, n = blk % N;
  int gz = n/(NG*NG), rn = n%(NG*NG), gy = rn/NG, gx = rn%NG;
  int lane = threadIdx.x;
  const float* mf = mindF + (size_t)b*12*VOL;
  float ss = 0.f;
  for (int j=lane; j<C; j+=64) {
    int c = j/(P*P*P); int r = j%(P*P*P); int dz = r/(P*P); int r2 = r%(P*P); int dy = r2/P; int dx = r2%P;
    float v = mf[(size_t)c*VOL + (size_t)(gz*P+dz)*SL + (size_t)(gy*P+dy)*RW + (gx*P+dx)];
    pa[j] = v; ss += v*v;
  }
  #pragma unroll
  for (int o=32;o;o>>=1) ss += __shfl_xor(ss, o);
  float inv_a = 1.0f/fmaxf(sqrtf(ss), 1e-12f);
  __syncthreads();
  int z0 = max(gz-R,0), z1 = min(gz+R,NG-1);
  int y0 = max(gy-R,0), y1 = min(gy+R,NG-1);
  int x0 = max(gx-R,0), x1 = min(gx+R,NG-1);
  int cy = y1-y0+1, cx = x1-x0+1, M = (z1-z0+1)*cy*cx;
  const float* pbb  = packedM + (size_t)b*N*C;
  const float* invb = invB + b*N;
  const float4* pa4 = (const float4*)pa;
  float sumE = 0.f, alg = -3.0e38f;
  for (int mi=lane; mi<M; mi+=64) {
    int iz = mi/(cy*cx); int rm = mi%(cy*cx); int iy = rm/cx; int ix = rm%cx;
    int m = ((z0+iz)*NG + (y0+iy))*NG + (x0+ix);
    const float4* pb4 = (const float4*)(pbb + (size_t)m*C);
    float a0 = 0.f;
    #pragma unroll 8
    for (int k=0;k<C/4;++k) {
      float4 a = pa4[k]; float4 bv = pb4[k];
      a0 += a.x*bv.x; a0 += a.y*bv.y; a0 += a.z*bv.z; a0 += a.w*bv.w;
    }
    float sim = a0 * inv_a * invb[m];   // sims in [-1,1]: safe to sum exp directly
    sumE += __expf(sim);
    if (m == n) alg = sim;
  }
  #pragma unroll
  for (int o=32;o;o>>=1) sumE += __shfl_xor(sumE, o);
  #pragma unroll
  for (int o=32;o;o>>=1) alg = fmaxf(alg, __shfl_xor(alg, o));
  if (lane==0) atomicAdd(acc, __logf(sumE) - alg);
}

__global__ void final_kernel(const float* __restrict__ sb, const float* __restrict__ sw,
                             float* __restrict__ out) {
  float w0 = sw[0], w1 = sw[1], w2 = sw[2];
  float mx = fmaxf(w0, fmaxf(w1, w2));
  float e0 = __expf(w0-mx), e1 = __expf(w1-mx), e2 = __expf(w2-mx);
  float se = e0+e1+e2;
  out[0] = (e0*sb[2]*(1.0f/(2.0f*27000.0f))
          + e1*sb[3]*(1.0f/(2.0f*5832.0f))
          + e2*sb[4]*(1.0f/(2.0f*1000.0f))) / se;
}

static inline int cdiv(long long a, int b) { return (int)((a + b - 1) / b); }

template<int P, int R>
static void run_scale(const float* mindF, const float* mindM, float* packed, float* invb,
                      float* acc, hipStream_t s) {
  constexpr int NG = 90/P, N = NG*NG*NG, C = 12*P*P*P;
  pack_kernel<P><<<cdiv((long long)2*N*C,256),256,0,s>>>(mindM, packed);
  norm_kernel<C><<<2*N,64,0,s>>>(packed, invb);
  loss_kernel<P,R><<<2*N,64,0,s>>>(mindF, packed, invb, acc);
}

extern "C" void kernel_launch(void* const* d_in, const int* in_sizes, int n_in,
                              void* d_out, int out_size, void* d_ws, size_t ws_size,
                              hipStream_t stream) {
  const float* fixedI  = (const float*)d_in[0];
  const float* movingI = (const float*)d_in[1];
  const float* scale_w = (const float*)d_in[2];
  float* out = (float*)d_out;

  // ws layout: [0..63] floats small accumulators | invb (54000 f) | A | B | C (17,496,000 f each)
  uint8_t* w = (uint8_t*)d_ws;
  float* smallb = (float*)w;                 // [0]=mvsum_f [1]=mvsum_m [2..4]=loss acc
  float* invb   = (float*)(w + 256);
  float* A      = (float*)(w + 256 + 216320);
  float* B      = A + (size_t)17496000;
  float* Cb     = B + (size_t)17496000;

  hipMemsetAsync(d_ws, 0, 256, stream);

  const int gE = cdiv(17496000, 256);
  const int gV = cdiv(1458000, 256);

  // MIND(fixed) -> B
  diff2_kernel<<<gE,256,0,stream>>>(fixedI, A);
  boxz_kernel<<<gE,256,0,stream>>>(A, B);
  boxy_kernel<<<gE,256,0,stream>>>(B, A);
  boxx_min_kernel<<<gV,256,0,stream>>>(A, B, smallb+0);
  finalize_kernel<<<gV,256,0,stream>>>(B, smallb+0);

  // MIND(moving) -> Cb
  diff2_kernel<<<gE,256,0,stream>>>(movingI, A);
  boxz_kernel<<<gE,256,0,stream>>>(A, Cb);
  boxy_kernel<<<gE,256,0,stream>>>(Cb, A);
  boxx_min_kernel<<<gV,256,0,stream>>>(A, Cb, smallb+1);
  finalize_kernel<<<gV,256,0,stream>>>(Cb, smallb+1);

  // per-scale losses (channel reorder skipped: loss is channel-permutation invariant)
  run_scale<3,3>(B, Cb, A, invb, smallb+2, stream);
  run_scale<5,2>(B, Cb, A, invb, smallb+3, stream);
  run_scale<9,1>(B, Cb, A, invb, smallb+4, stream);

  final_kernel<<<1,1,0,stream>>>(smallb, scale_w, out);
}

// Round 3
// 1726.317 us; speedup vs baseline: 3.1552x; 3.1552x over previous
//
#include <hip/hip_runtime.h>
#include <hip/hip_bf16.h>
#include <math.h>

#define VOL 729000
#define SL  8100
#define RW  90

typedef __attribute__((ext_vector_type(8))) short s8v;
typedef __attribute__((ext_vector_type(4))) float f32x4;

// 12 offset pairs (dz,dy,dx), dilated (*2)
__device__ __constant__ int c_o1[12][3] = {
  {0,0,-2},{0,-2,0},{0,-2,0},{0,0,2},{0,0,2},{2,0,0},{2,0,0},{2,0,0},{0,2,0},{0,2,0},{0,2,0},{0,2,0}
};
__device__ __constant__ int c_o2[12][3] = {
  {-2,0,0},{-2,0,0},{0,0,-2},{-2,0,0},{0,-2,0},{0,0,-2},{0,-2,0},{0,0,2},{-2,0,0},{0,0,-2},{0,0,2},{2,0,0}
};

__device__ __forceinline__ int clampi(int v, int lo, int hi){ return v<lo?lo:(v>hi?hi:v); }

// fused diff2 + z-box (nested clamp == edge-pad semantics of reference)
__global__ void diff2z_kernel(const float* __restrict__ img, float* __restrict__ out) {
  int idx = blockIdx.x*256 + threadIdx.x;
  if (idx >= 2*12*VOL) return;
  int vox = idx % VOL; int ct = idx / VOL; int t = ct % 12, b = ct / 12;
  int z = vox / SL; int r = vox % SL; int y = r / RW; int x = r % RW;
  const float* im = img + (size_t)b*VOL;
  int o1z=c_o1[t][0], o1y=c_o1[t][1], o1x=c_o1[t][2];
  int o2z=c_o2[t][0], o2y=c_o2[t][1], o2x=c_o2[t][2];
  int y1 = clampi(y+o1y,0,89), x1 = clampi(x+o1x,0,89);
  int y2 = clampi(y+o2y,0,89), x2 = clampi(x+o2x,0,89);
  float s = 0.f;
  #pragma unroll
  for (int d=-2; d<=2; ++d) {
    int zz = clampi(z+d,0,89);
    int z1 = clampi(zz+o1z,0,89), z2 = clampi(zz+o2z,0,89);
    float dv = im[z1*SL+y1*RW+x1] - im[z2*SL+y2*RW+x2];
    s += dv*dv;
  }
  out[idx] = s;
}

__global__ void boxy_kernel(const float* __restrict__ in, float* __restrict__ out) {
  int idx = blockIdx.x*256 + threadIdx.x;
  if (idx >= 2*12*VOL) return;
  int vox = idx % VOL; int bc = idx / VOL;
  int z = vox / SL; int r = vox % SL; int y = r / RW; int x = r % RW;
  const float* p = in + (size_t)bc*VOL + (size_t)z*SL + x;
  float s = 0.f;
  #pragma unroll
  for (int d=-2; d<=2; ++d) { int yc = clampi(y+d,0,89); s += p[yc*RW]; }
  out[idx] = s;
}

// x box (/125), channel min, pre = ssd - min, accumulate sum of per-voxel mv
__global__ void boxxmin_kernel(const float* __restrict__ in, float* __restrict__ outPre,
                               float* __restrict__ mvsum) {
  __shared__ float red;
  if (threadIdx.x == 0) red = 0.f;
  __syncthreads();
  int idx = blockIdx.x*256 + threadIdx.x;
  float mv = 0.f;
  if (idx < 2*VOL) {
    int b = idx / VOL; int vox = idx % VOL;
    int z = vox / SL; int r = vox % SL; int y = r / RW; int x = r % RW;
    const float* base = in + (size_t)b*12*VOL + (size_t)z*SL + (size_t)y*RW;
    float s[12]; float mn = 3.4e38f;
    #pragma unroll
    for (int c=0;c<12;++c) {
      const float* pc = base + (size_t)c*VOL;
      float t = 0.f;
      #pragma unroll
      for (int d=-2;d<=2;++d) { int xc = clampi(x+d,0,89); t += pc[xc]; }
      t *= (1.0f/125.0f);
      s[c] = t; mn = fminf(mn, t);
    }
    float* ob = outPre + (size_t)b*12*VOL + vox;
    #pragma unroll
    for (int c=0;c<12;++c) { float pre = s[c]-mn; ob[(size_t)c*VOL] = pre; mv += pre; }
    mv *= (1.0f/12.0f);
  }
  #pragma unroll
  for (int o=32;o;o>>=1) mv += __shfl_xor(mv, o);
  if ((threadIdx.x & 63)==0 && mv != 0.f) atomicAdd(&red, mv);
  __syncthreads();
  if (threadIdx.x==0) atomicAdd(mvsum, red);
}

// pre -> exp(-pre / clip(mean_c(pre), mm*1e-3, mm*1e3)), X -> Y
__global__ void finalize_kernel(const float* __restrict__ pre, float* __restrict__ out,
                                const float* __restrict__ mvsum) {
  int idx = blockIdx.x*256 + threadIdx.x;
  if (idx >= 2*VOL) return;
  int b = idx / VOL; int vox = idx % VOL;
  const float* base = pre + (size_t)b*12*VOL + vox;
  float* ob = out + (size_t)b*12*VOL + vox;
  float s[12]; float mv = 0.f;
  #pragma unroll
  for (int c=0;c<12;++c) { s[c] = base[(size_t)c*VOL]; mv += s[c]; }
  mv *= (1.0f/12.0f);
  float mm = *mvsum * (1.0f/1458000.0f);
  float mvc = fminf(fmaxf(mv, mm*0.001f), mm*1000.0f);
  float inv = 1.0f / mvc;
  #pragma unroll
  for (int c=0;c<12;++c) ob[(size_t)c*VOL] = __expf(-s[c]*inv);
}

// pack + L2-normalize into bf16 packed descriptors [b*N+n][C]
template<int P>
__global__ __launch_bounds__(64) void pack_kernel(const float* __restrict__ mind,
                                                  ushort* __restrict__ out) {
  constexpr int NG=90/P, N=NG*NG*NG, C=12*P*P*P;
  int d = blockIdx.x;                 // 0..2N
  int b = d / N, n = d % N;
  int gz = n/(NG*NG), rn = n%(NG*NG), gy = rn/NG, gx = rn%NG;
  const float* mf = mind + (size_t)b*12*VOL + (size_t)gz*P*SL + (size_t)gy*P*RW + gx*P;
  int lane = threadIdx.x;
  float ss = 0.f;
  for (int j = lane; j < C; j += 64) {
    int c = j/(P*P*P); int r = j%(P*P*P); int dz = r/(P*P); int r2 = r%(P*P); int dy = r2/P; int dx = r2%P;
    float v = mf[(size_t)c*VOL + dz*SL + dy*RW + dx];
    ss += v*v;
  }
  #pragma unroll
  for (int o=32;o;o>>=1) ss += __shfl_xor(ss, o);
  float inv = 1.0f/fmaxf(sqrtf(ss), 1e-12f);
  ushort* ob = out + (size_t)d*C;
  for (int j = lane; j < C; j += 64) {
    int c = j/(P*P*P); int r = j%(P*P*P); int dz = r/(P*P); int r2 = r%(P*P); int dy = r2/P; int dx = r2%P;
    float v = mf[(size_t)c*VOL + dz*SL + dy*RW + dx] * inv;
    __hip_bfloat16 h = __float2bfloat16(v);
    ob[j] = *(ushort*)&h;
  }
}

union FragU { s8v s; uint u[4]; };

__device__ __forceinline__ s8v ldfrag(const ushort* p) {
  FragU f;
  uint2 a = *(const uint2*)p;
  uint2 b = *(const uint2*)(p + 4);
  f.u[0]=a.x; f.u[1]=a.y; f.u[2]=b.x; f.u[3]=b.y;
  return f.s;
}
__device__ __forceinline__ s8v ldfrag_m(const ushort* p, bool v0, bool v1) {
  FragU f;
  if (v0) { uint2 a = *(const uint2*)p;     f.u[0]=a.x; f.u[1]=a.y; } else { f.u[0]=0; f.u[1]=0; }
  if (v1) { uint2 b = *(const uint2*)(p+4); f.u[2]=b.x; f.u[3]=b.y; } else { f.u[2]=0; f.u[3]=0; }
  return f.s;
}

// block = (b,gz,gy): 16*NRT MFMA rows cover x=0..NG-1; B-union streamed in 16-desc chunks.
template<int P, int R, int NRT, bool SA>
__global__ __launch_bounds__(512) void loss_kernel(
    const ushort* __restrict__ pkF, const ushort* __restrict__ pkM, float* __restrict__ acc) {
  constexpr int NG=90/P, N=NG*NG*NG, C=12*P*P*P;
  constexpr int KFULL = (C/32)*32;
  constexpr int NROWS = NRT*16;
  static_assert(NROWS >= NG, "need enough MFMA rows to cover the x line");
  __shared__ __align__(16) ushort aTile[SA ? NG*C : 4];
  __shared__ float sumS[NROWS];
  __shared__ float alnS[NROWS];
  int blk = blockIdx.x;
  int gy = blk % NG; int t1 = blk / NG; int gz = t1 % NG; int b = t1 / NG;
  int tid = threadIdx.x; int lane = tid & 63; int wv = tid >> 6;
  int col = lane & 15, grp = lane >> 4;
  size_t baseF = ((size_t)b*N + ((size_t)gz*NG + gy)*NG) * C;
  for (int i = tid; i < NROWS; i += 512) { sumS[i]=0.f; alnS[i]=0.f; }
  if constexpr (SA) {
    const uint2* src = (const uint2*)(pkF + baseF);
    uint2* dst = (uint2*)aTile;
    for (int i = tid; i < NG*C/4; i += 512) dst[i] = src[i];
  }
  __syncthreads();
  const ushort* aBase[NRT];
  #pragma unroll
  for (int t=0;t<NRT;++t) {
    int row = t*16 + col; if (row > NG-1) row = NG-1;   // A row = lane&15 (M dim)
    if constexpr (SA) aBase[t] = (const ushort*)aTile + (size_t)row*C;
    else              aBase[t] = pkF + baseF + (size_t)row*C;
  }
  int z0 = max(gz-R,0), z1 = min(gz+R,NG-1);
  int y0 = max(gy-R,0), y1 = min(gy+R,NG-1);
  int wy = y1-y0+1;
  int Mu = (z1-z0+1)*wy*NG;
  int nch = (Mu+15)>>4;
  float sumE[NRT][4];
  #pragma unroll
  for (int t=0;t<NRT;++t) { sumE[t][0]=0.f; sumE[t][1]=0.f; sumE[t][2]=0.f; sumE[t][3]=0.f; }
  const int ko = grp*8;
  for (int mc = wv; mc < nch; mc += 8) {
    int mu = mc*16 + col; bool vm = mu < Mu;
    int mus = vm ? mu : 0;
    int mz = z0 + mus/(wy*NG); int rm = mus%(wy*NG); int myq = rm/NG;
    int my = y0 + myq; int mx = rm - myq*NG;
    const ushort* pb = pkM + ((size_t)b*N + ((size_t)mz*NG+my)*NG + mx)*C;
    f32x4 accv[NRT];
    #pragma unroll
    for (int t=0;t<NRT;++t) accv[t] = (f32x4){0.f,0.f,0.f,0.f};
    for (int kk = 0; kk < KFULL; kk += 32) {
      s8v bf = ldfrag(pb + kk + ko);
      #pragma unroll
      for (int t=0;t<NRT;++t) {
        s8v af = ldfrag(aBase[t] + kk + ko);
        accv[t] = __builtin_amdgcn_mfma_f32_16x16x32_bf16(af, bf, accv[t], 0,0,0);
      }
    }
    if constexpr ((C & 31) != 0) {
      int k0 = KFULL + ko;
      bool v0 = k0 < C, v1 = (k0+4) < C;
      s8v bf = ldfrag_m(pb + k0, v0, v1);
      #pragma unroll
      for (int t=0;t<NRT;++t) {
        s8v af = ldfrag_m(aBase[t] + k0, v0, v1);
        accv[t] = __builtin_amdgcn_mfma_f32_16x16x32_bf16(af, bf, accv[t], 0,0,0);
      }
    }
    #pragma unroll
    for (int t=0;t<NRT;++t) {
      #pragma unroll
      for (int j=0;j<4;++j) {
        int x = t*16 + grp*4 + j;                      // D row = (lane>>4)*4 + reg
        float sim = accv[t][j];
        bool ok = vm && (x < NG) && (mx - x <= R) && (x - mx <= R);
        if (ok) {
          sumE[t][j] += __expf(sim);
          if (mz==gz && my==gy && mx==x) alnS[x] = sim;
        }
      }
    }
  }
  #pragma unroll
  for (int t=0;t<NRT;++t) {
    #pragma unroll
    for (int j=0;j<4;++j) {
      float v = sumE[t][j];
      v += __shfl_xor(v,1); v += __shfl_xor(v,2); v += __shfl_xor(v,4); v += __shfl_xor(v,8);
      if (col==0) atomicAdd(&sumS[t*16 + grp*4 + j], v);
    }
  }
  __syncthreads();
  if (tid < 64) {
    float v = 0.f;
    if (tid < NG) v = __logf(sumS[tid]) - alnS[tid];
    v += __shfl_xor(v,1); v += __shfl_xor(v,2); v += __shfl_xor(v,4);
    v += __shfl_xor(v,8); v += __shfl_xor(v,16); v += __shfl_xor(v,32);
    if (tid==0) atomicAdd(acc, v);
  }
}

__global__ void final_kernel(const float* __restrict__ sb, const float* __restrict__ sw,
                             float* __restrict__ out) {
  float w0 = sw[0], w1 = sw[1], w2 = sw[2];
  float mx = fmaxf(w0, fmaxf(w1, w2));
  float e0 = __expf(w0-mx), e1 = __expf(w1-mx), e2 = __expf(w2-mx);
  float se = e0+e1+e2;
  out[0] = (e0*sb[2]*(1.0f/(2.0f*27000.0f))
          + e1*sb[3]*(1.0f/(2.0f*5832.0f))
          + e2*sb[4]*(1.0f/(2.0f*1000.0f))) / se;
}

static inline int cdiv(long long a, int b) { return (int)((a + b - 1) / b); }

template<int P, int R, int NRT, bool SA>
static void run_scale(const float* Yf, const float* Ym, ushort* pkF, ushort* pkM,
                      float* acc, hipStream_t s) {
  constexpr int NG=90/P, N=NG*NG*NG;
  pack_kernel<P><<<2*N, 64, 0, s>>>(Yf, pkF);
  pack_kernel<P><<<2*N, 64, 0, s>>>(Ym, pkM);
  loss_kernel<P,R,NRT,SA><<<2*NG*NG, 512, 0, s>>>(pkF, pkM, acc);
}

extern "C" void kernel_launch(void* const* d_in, const int* in_sizes, int n_in,
                              void* d_out, int out_size, void* d_ws, size_t ws_size,
                              hipStream_t stream) {
  const float* fixedI  = (const float*)d_in[0];
  const float* movingI = (const float*)d_in[1];
  const float* scale_w = (const float*)d_in[2];
  float* out = (float*)d_out;

  // ws: [0,4096) small | PK (69,984,000 B, aliases fp32 scratch X) | Yf | Ym
  uint8_t* w = (uint8_t*)d_ws;
  float*  smallb = (float*)w;                       // [0]=mv_f [1]=mv_m [2..4]=loss
  ushort* PK  = (ushort*)(w + 4096);
  float*  X   = (float*)(w + 4096);                 // alias of PK region
  float*  Yf  = (float*)(w + 4096 + 69984000);
  float*  Ym  = Yf + 17496000;
  ushort* pkF = PK;
  ushort* pkM = PK + 17496000;

  hipMemsetAsync(smallb, 0, 4096, stream);

  const int gE = cdiv(17496000, 256);
  const int gV = cdiv(1458000, 256);

  // MIND(fixed) -> Yf
  diff2z_kernel<<<gE,256,0,stream>>>(fixedI, X);
  boxy_kernel<<<gE,256,0,stream>>>(X, Yf);
  boxxmin_kernel<<<gV,256,0,stream>>>(Yf, X, smallb+0);
  finalize_kernel<<<gV,256,0,stream>>>(X, Yf, smallb+0);

  // MIND(moving) -> Ym
  diff2z_kernel<<<gE,256,0,stream>>>(movingI, X);
  boxy_kernel<<<gE,256,0,stream>>>(X, Ym);
  boxxmin_kernel<<<gV,256,0,stream>>>(Ym, X, smallb+1);
  finalize_kernel<<<gV,256,0,stream>>>(X, Ym, smallb+1);

  // per-scale (X dead now; PK region reused per scale)
  run_scale<3,3,2,true >(Yf, Ym, pkF, pkM, smallb+2, stream);
  run_scale<5,2,2,true >(Yf, Ym, pkF, pkM, smallb+3, stream);
  run_scale<9,1,1,false>(Yf, Ym, pkF, pkM, smallb+4, stream);

  final_kernel<<<1,1,0,stream>>>(smallb, scale_w, out);
}

// Round 4
// 1643.479 us; speedup vs baseline: 3.3143x; 1.0504x over previous
//
#include <hip/hip_runtime.h>
#include <hip/hip_bf16.h>
#include <math.h>

#define VOL 729000
#define SL  8100
#define RW  90

typedef __attribute__((ext_vector_type(8))) short s8v;
typedef __attribute__((ext_vector_type(4))) float f32x4;

__device__ __constant__ int c_o1[12][3] = {
  {0,0,-2},{0,-2,0},{0,-2,0},{0,0,2},{0,0,2},{2,0,0},{2,0,0},{2,0,0},{0,2,0},{0,2,0},{0,2,0},{0,2,0}
};
__device__ __constant__ int c_o2[12][3] = {
  {-2,0,0},{-2,0,0},{0,0,-2},{-2,0,0},{0,-2,0},{0,0,-2},{0,-2,0},{0,0,2},{-2,0,0},{0,0,-2},{0,0,2},{2,0,0}
};

__device__ __forceinline__ int clampi(int v, int lo, int hi){ return v<lo?lo:(v>hi?hi:v); }

__global__ void diff2z_kernel(const float* __restrict__ img, float* __restrict__ out) {
  int idx = blockIdx.x*256 + threadIdx.x;
  if (idx >= 2*12*VOL) return;
  int vox = idx % VOL; int ct = idx / VOL; int t = ct % 12, b = ct / 12;
  int z = vox / SL; int r = vox % SL; int y = r / RW; int x = r % RW;
  const float* im = img + (size_t)b*VOL;
  int o1z=c_o1[t][0], o1y=c_o1[t][1], o1x=c_o1[t][2];
  int o2z=c_o2[t][0], o2y=c_o2[t][1], o2x=c_o2[t][2];
  int y1 = clampi(y+o1y,0,89), x1 = clampi(x+o1x,0,89);
  int y2 = clampi(y+o2y,0,89), x2 = clampi(x+o2x,0,89);
  float s = 0.f;
  #pragma unroll
  for (int d=-2; d<=2; ++d) {
    int zz = clampi(z+d,0,89);
    int z1 = clampi(zz+o1z,0,89), z2 = clampi(zz+o2z,0,89);
    float dv = im[z1*SL+y1*RW+x1] - im[z2*SL+y2*RW+x2];
    s += dv*dv;
  }
  out[idx] = s;
}

__global__ void boxy_kernel(const float* __restrict__ in, float* __restrict__ out) {
  int idx = blockIdx.x*256 + threadIdx.x;
  if (idx >= 2*12*VOL) return;
  int vox = idx % VOL; int bc = idx / VOL;
  int z = vox / SL; int r = vox % SL; int y = r / RW; int x = r % RW;
  const float* p = in + (size_t)bc*VOL + (size_t)z*SL + x;
  float s = 0.f;
  #pragma unroll
  for (int d=-2; d<=2; ++d) { int yc = clampi(y+d,0,89); s += p[yc*RW]; }
  out[idx] = s;
}

__global__ void boxxmin_kernel(const float* __restrict__ in, float* __restrict__ outPre,
                               float* __restrict__ mvsum) {
  __shared__ float red;
  if (threadIdx.x == 0) red = 0.f;
  __syncthreads();
  int idx = blockIdx.x*256 + threadIdx.x;
  float mv = 0.f;
  if (idx < 2*VOL) {
    int b = idx / VOL; int vox = idx % VOL;
    int z = vox / SL; int r = vox % SL; int y = r / RW; int x = r % RW;
    const float* base = in + (size_t)b*12*VOL + (size_t)z*SL + (size_t)y*RW;
    float s[12]; float mn = 3.4e38f;
    #pragma unroll
    for (int c=0;c<12;++c) {
      const float* pc = base + (size_t)c*VOL;
      float t = 0.f;
      #pragma unroll
      for (int d=-2;d<=2;++d) { int xc = clampi(x+d,0,89); t += pc[xc]; }
      t *= (1.0f/125.0f);
      s[c] = t; mn = fminf(mn, t);
    }
    float* ob = outPre + (size_t)b*12*VOL + vox;
    #pragma unroll
    for (int c=0;c<12;++c) { float pre = s[c]-mn; ob[(size_t)c*VOL] = pre; mv += pre; }
    mv *= (1.0f/12.0f);
  }
  #pragma unroll
  for (int o=32;o;o>>=1) mv += __shfl_xor(mv, o);
  if ((threadIdx.x & 63)==0 && mv != 0.f) atomicAdd(&red, mv);
  __syncthreads();
  if (threadIdx.x==0) atomicAdd(mvsum, red);
}

__global__ void finalize_kernel(const float* __restrict__ pre, float* __restrict__ out,
                                const float* __restrict__ mvsum) {
  int idx = blockIdx.x*256 + threadIdx.x;
  if (idx >= 2*VOL) return;
  int b = idx / VOL; int vox = idx % VOL;
  const float* base = pre + (size_t)b*12*VOL + vox;
  float* ob = out + (size_t)b*12*VOL + vox;
  float s[12]; float mv = 0.f;
  #pragma unroll
  for (int c=0;c<12;++c) { s[c] = base[(size_t)c*VOL]; mv += s[c]; }
  mv *= (1.0f/12.0f);
  float mm = *mvsum * (1.0f/1458000.0f);
  float mvc = fminf(fmaxf(mv, mm*0.001f), mm*1000.0f);
  float inv = 1.0f / mvc;
  #pragma unroll
  for (int c=0;c<12;++c) ob[(size_t)c*VOL] = __expf(-s[c]*inv);
}

template<int P>
__global__ __launch_bounds__(64) void pack_kernel(const float* __restrict__ mind,
                                                  ushort* __restrict__ out) {
  constexpr int NG=90/P, N=NG*NG*NG, C=12*P*P*P;
  int d = blockIdx.x;
  int b = d / N, n = d % N;
  int gz = n/(NG*NG), rn = n%(NG*NG), gy = rn/NG, gx = rn%NG;
  const float* mf = mind + (size_t)b*12*VOL + (size_t)gz*P*SL + (size_t)gy*P*RW + gx*P;
  int lane = threadIdx.x;
  float ss = 0.f;
  for (int j = lane; j < C; j += 64) {
    int c = j/(P*P*P); int r = j%(P*P*P); int dz = r/(P*P); int r2 = r%(P*P); int dy = r2/P; int dx = r2%P;
    float v = mf[(size_t)c*VOL + dz*SL + dy*RW + dx];
    ss += v*v;
  }
  #pragma unroll
  for (int o=32;o;o>>=1) ss += __shfl_xor(ss, o);
  float inv = 1.0f/fmaxf(sqrtf(ss), 1e-12f);
  ushort* ob = out + (size_t)d*C;
  for (int j = lane; j < C; j += 64) {
    int c = j/(P*P*P); int r = j%(P*P*P); int dz = r/(P*P); int r2 = r%(P*P); int dy = r2/P; int dx = r2%P;
    float v = mf[(size_t)c*VOL + dz*SL + dy*RW + dx] * inv;
    __hip_bfloat16 h = __float2bfloat16(v);
    ob[j] = *(ushort*)&h;
  }
}

union FragU { s8v s; uint u[4]; };

__device__ __forceinline__ s8v ldfrag(const ushort* p) {
  FragU f;
  uint2 a = *(const uint2*)p;
  uint2 b = *(const uint2*)(p + 4);
  f.u[0]=a.x; f.u[1]=a.y; f.u[2]=b.x; f.u[3]=b.y;
  return f.s;
}
__device__ __forceinline__ s8v ldfrag_m(const ushort* p, bool v0, bool v1) {
  FragU f;
  if (v0) { uint2 a = *(const uint2*)p;     f.u[0]=a.x; f.u[1]=a.y; } else { f.u[0]=0; f.u[1]=0; }
  if (v1) { uint2 b = *(const uint2*)(p+4); f.u[2]=b.x; f.u[3]=b.y; } else { f.u[2]=0; f.u[3]=0; }
  return f.s;
}

// block = (b, mz-plane, gy, j) with gz = mz-R+j. Plane-major block order + bijective
// XCD swizzle => all blocks reading B-plane mz (<= 1 MB) co-resident per XCD L2.
// Partial exp-sums accumulated to global sumG; aligned sim stored once (mz==gz block).
template<int P, int R, int NRT, int TPB>
__global__ __launch_bounds__(TPB) void loss_kernel(
    const ushort* __restrict__ pkF, const ushort* __restrict__ pkM,
    float* __restrict__ sumG, float* __restrict__ alnG) {
  constexpr int NG=90/P, N=NG*NG*NG, C=12*P*P*P;
  constexpr int KFULL = (C/32)*32;
  constexpr int NROWS = NRT*16;
  constexpr int NW = TPB/64;
  constexpr int WZ = 2*R+1;
  static_assert(NROWS >= NG, "row tiles must cover the x line");
  __shared__ float sumS[NROWS];
  // bijective XCD swizzle (m204): contiguous lid chunks per XCD
  int nwg = gridDim.x;
  int q = nwg >> 3, r8 = nwg & 7;
  int xcd = blockIdx.x & 7, sidx = blockIdx.x >> 3;
  int lid = (xcd < r8 ? xcd*(q+1) : r8*(q+1) + (xcd - r8)*q) + sidx;
  int j = lid % WZ; int t1 = lid / WZ;
  int gy = t1 % NG; t1 /= NG;
  int mz = t1 % NG; int b = t1 / NG;
  int gz = mz - R + j;
  if (gz < 0 || gz >= NG) return;
  int tid = threadIdx.x; int lane = tid & 63; int wv = tid >> 6;
  int col = lane & 15, grp = lane >> 4;
  for (int i = tid; i < NROWS; i += TPB) sumS[i] = 0.f;
  __syncthreads();
  size_t baseF = ((size_t)b*N + ((size_t)gz*NG + gy)*NG) * C;
  const ushort* aBase[NRT];
  #pragma unroll
  for (int t=0;t<NRT;++t) {
    int row = t*16 + col; if (row > NG-1) row = NG-1;
    aBase[t] = pkF + baseF + (size_t)row*C;
  }
  int y0 = max(gy-R,0), y1 = min(gy+R,NG-1);
  int wy = y1-y0+1;
  int Ms = wy*NG;                      // descriptors in this (mz, y-window) slice; contiguous
  int nch = (Ms+15)>>4;
  const ushort* sliceM = pkM + ((size_t)b*N + ((size_t)mz*NG + y0)*NG) * C;
  float* lineSum = sumG + (size_t)b*N + ((size_t)gz*NG + gy)*NG;
  float* lineAln = alnG + (size_t)b*N + ((size_t)gz*NG + gy)*NG;
  float sumE[NRT][4];
  #pragma unroll
  for (int t=0;t<NRT;++t) { sumE[t][0]=0.f; sumE[t][1]=0.f; sumE[t][2]=0.f; sumE[t][3]=0.f; }
  const int ko = grp*8;
  for (int mc = wv; mc < nch; mc += NW) {
    int mu = mc*16 + col; bool vm = mu < Ms;
    int mus = vm ? mu : 0;
    int my = y0 + mus/NG; int mx = mus - (mus/NG)*NG;
    const ushort* pb = sliceM + (size_t)mus*C;
    f32x4 accv[NRT];
    #pragma unroll
    for (int t=0;t<NRT;++t) accv[t] = (f32x4){0.f,0.f,0.f,0.f};
    for (int kk = 0; kk < KFULL; kk += 32) {
      s8v bf = ldfrag(pb + kk + ko);
      #pragma unroll
      for (int t=0;t<NRT;++t) {
        s8v af = ldfrag(aBase[t] + kk + ko);
        accv[t] = __builtin_amdgcn_mfma_f32_16x16x32_bf16(af, bf, accv[t], 0,0,0);
      }
    }
    if constexpr ((C & 31) != 0) {
      int k0 = KFULL + ko;
      bool v0 = k0 < C, v1 = (k0+4) < C;
      s8v bf = ldfrag_m(pb + k0, v0, v1);
      #pragma unroll
      for (int t=0;t<NRT;++t) {
        s8v af = ldfrag_m(aBase[t] + k0, v0, v1);
        accv[t] = __builtin_amdgcn_mfma_f32_16x16x32_bf16(af, bf, accv[t], 0,0,0);
      }
    }
    #pragma unroll
    for (int t=0;t<NRT;++t) {
      #pragma unroll
      for (int jj=0;jj<4;++jj) {
        int x = t*16 + grp*4 + jj;                 // D row = (lane>>4)*4 + reg
        float sim = accv[t][jj];
        bool ok = vm && (x < NG) && (mx - x <= R) && (x - mx <= R);
        if (ok) {
          sumE[t][jj] += __expf(sim);
          if (mz==gz && my==gy && mx==x) lineAln[x] = sim;
        }
      }
    }
  }
  #pragma unroll
  for (int t=0;t<NRT;++t) {
    #pragma unroll
    for (int jj=0;jj<4;++jj) {
      float v = sumE[t][jj];
      v += __shfl_xor(v,1); v += __shfl_xor(v,2); v += __shfl_xor(v,4); v += __shfl_xor(v,8);
      if (col==0) atomicAdd(&sumS[t*16 + grp*4 + jj], v);
    }
  }
  __syncthreads();
  if (tid < NG) {
    float v = sumS[tid];
    if (v != 0.f) atomicAdd(&lineSum[tid], v);
  }
}

// one pass over all three scales' (sum, aln) arrays -> weighted loss into out[0]
__global__ void epilogue_kernel(const float* __restrict__ sumG, const float* __restrict__ alnG,
                                const float* __restrict__ sw, float* __restrict__ out) {
  constexpr int N3 = 54000, N5 = 11664, N9 = 2000;   // 2*N per scale
  constexpr int TOT = N3 + N5 + N9;
  __shared__ float wred[4];
  int idx = blockIdx.x*256 + threadIdx.x;
  float w0 = sw[0], w1 = sw[1], w2 = sw[2];
  float mx = fmaxf(w0, fmaxf(w1, w2));
  float e0 = __expf(w0-mx), e1 = __expf(w1-mx), e2 = __expf(w2-mx);
  float ise = 1.0f/(e0+e1+e2);
  float c = 0.f;
  if (idx < TOT) {
    float coef;
    if (idx < N3)            coef = e0*ise/(float)N3;
    else if (idx < N3+N5)    coef = e1*ise/(float)N5;
    else                     coef = e2*ise/(float)N9;
    c = (__logf(sumG[idx]) - alnG[idx]) * coef;
  }
  #pragma unroll
  for (int o=32;o;o>>=1) c += __shfl_xor(c, o);
  if ((threadIdx.x & 63)==0) wred[threadIdx.x>>6] = c;
  __syncthreads();
  if (threadIdx.x==0) {
    float s = wred[0]+wred[1]+wred[2]+wred[3];
    if (s != 0.f) atomicAdd(out, s);
  }
}

static inline int cdiv(long long a, int b) { return (int)((a + b - 1) / b); }

template<int P, int R, int NRT, int TPB>
static void run_scale(const float* Yf, const float* Ym, ushort* pkF, ushort* pkM,
                      float* sumG, float* alnG, hipStream_t s) {
  constexpr int NG=90/P, N=NG*NG*NG;
  pack_kernel<P><<<2*N, 64, 0, s>>>(Yf, pkF);
  pack_kernel<P><<<2*N, 64, 0, s>>>(Ym, pkM);
  loss_kernel<P,R,NRT,TPB><<<2*NG*NG*(2*R+1), TPB, 0, s>>>(pkF, pkM, sumG, alnG);
}

extern "C" void kernel_launch(void* const* d_in, const int* in_sizes, int n_in,
                              void* d_out, int out_size, void* d_ws, size_t ws_size,
                              hipStream_t stream) {
  const float* fixedI  = (const float*)d_in[0];
  const float* movingI = (const float*)d_in[1];
  const float* scale_w = (const float*)d_in[2];
  float* out = (float*)d_out;

  // ws: [0,4096) small | sumG (67664 f) | alnG (67664 f) | @1MB: PK (70 MB) | Yf | Ym
  uint8_t* w = (uint8_t*)d_ws;
  float*  smallb = (float*)w;                    // [0]=mv_f [1]=mv_m
  float*  sumG = (float*)(w + 4096);
  float*  alnG = sumG + 67664;
  ushort* PK  = (ushort*)(w + (1u<<20));
  float*  X   = (float*)(w + (1u<<20));          // alias of PK
  float*  Yf  = (float*)(w + (1u<<20) + 69984000);
  float*  Ym  = Yf + 17496000;
  ushort* pkF = PK;
  ushort* pkM = PK + 17496000;

  hipMemsetAsync(w, 0, 4096 + 67664*4, stream);  // smallb + sumG (alnG always overwritten)
  hipMemsetAsync(d_out, 0, sizeof(float), stream);

  const int gE = cdiv(17496000, 256);
  const int gV = cdiv(1458000, 256);

  diff2z_kernel<<<gE,256,0,stream>>>(fixedI, X);
  boxy_kernel<<<gE,256,0,stream>>>(X, Yf);
  boxxmin_kernel<<<gV,256,0,stream>>>(Yf, X, smallb+0);
  finalize_kernel<<<gV,256,0,stream>>>(X, Yf, smallb+0);

  diff2z_kernel<<<gE,256,0,stream>>>(movingI, X);
  boxy_kernel<<<gE,256,0,stream>>>(X, Ym);
  boxxmin_kernel<<<gV,256,0,stream>>>(Ym, X, smallb+1);
  finalize_kernel<<<gV,256,0,stream>>>(X, Ym, smallb+1);

  run_scale<3,3,2,256>(Yf, Ym, pkF, pkM, sumG,          alnG,          stream);
  run_scale<5,2,2,256>(Yf, Ym, pkF, pkM, sumG + 54000,  alnG + 54000,  stream);
  run_scale<9,1,1,128>(Yf, Ym, pkF, pkM, sumG + 65664,  alnG + 65664,  stream);

  epilogue_kernel<<<cdiv(67664,256),256,0,stream>>>(sumG, alnG, scale_w, out);
}

// Round 5
// 1632.744 us; speedup vs baseline: 3.3361x; 1.0066x over previous
//
#include <hip/hip_runtime.h>
#include <hip/hip_bf16.h>
#include <math.h>

#define VOL 729000
#define SL  8100
#define RW  90

typedef __attribute__((ext_vector_type(8))) short s8v;
typedef __attribute__((ext_vector_type(4))) float f32x4;

__device__ __constant__ int c_o1[12][3] = {
  {0,0,-2},{0,-2,0},{0,-2,0},{0,0,2},{0,0,2},{2,0,0},{2,0,0},{2,0,0},{0,2,0},{0,2,0},{0,2,0},{0,2,0}
};
__device__ __constant__ int c_o2[12][3] = {
  {-2,0,0},{-2,0,0},{0,0,-2},{-2,0,0},{0,-2,0},{0,0,-2},{0,-2,0},{0,0,2},{-2,0,0},{0,0,-2},{0,0,2},{2,0,0}
};

__device__ __forceinline__ int clampi(int v, int lo, int hi){ return v<lo?lo:(v>hi?hi:v); }

__global__ void diff2z_kernel(const float* __restrict__ img, float* __restrict__ out) {
  int idx = blockIdx.x*256 + threadIdx.x;
  if (idx >= 2*12*VOL) return;
  int vox = idx % VOL; int ct = idx / VOL; int t = ct % 12, b = ct / 12;
  int z = vox / SL; int r = vox % SL; int y = r / RW; int x = r % RW;
  const float* im = img + (size_t)b*VOL;
  int o1z=c_o1[t][0], o1y=c_o1[t][1], o1x=c_o1[t][2];
  int o2z=c_o2[t][0], o2y=c_o2[t][1], o2x=c_o2[t][2];
  int y1 = clampi(y+o1y,0,89), x1 = clampi(x+o1x,0,89);
  int y2 = clampi(y+o2y,0,89), x2 = clampi(x+o2x,0,89);
  float s = 0.f;
  #pragma unroll
  for (int d=-2; d<=2; ++d) {
    int zz = clampi(z+d,0,89);
    int z1 = clampi(zz+o1z,0,89), z2 = clampi(zz+o2z,0,89);
    float dv = im[z1*SL+y1*RW+x1] - im[z2*SL+y2*RW+x2];
    s += dv*dv;
  }
  out[idx] = s;
}

__global__ void boxy_kernel(const float* __restrict__ in, float* __restrict__ out) {
  int idx = blockIdx.x*256 + threadIdx.x;
  if (idx >= 2*12*VOL) return;
  int vox = idx % VOL; int bc = idx / VOL;
  int z = vox / SL; int r = vox % SL; int y = r / RW; int x = r % RW;
  const float* p = in + (size_t)bc*VOL + (size_t)z*SL + x;
  float s = 0.f;
  #pragma unroll
  for (int d=-2; d<=2; ++d) { int yc = clampi(y+d,0,89); s += p[yc*RW]; }
  out[idx] = s;
}

__global__ void boxxmin_kernel(const float* __restrict__ in, float* __restrict__ outPre,
                               float* __restrict__ mvsum) {
  __shared__ float red;
  if (threadIdx.x == 0) red = 0.f;
  __syncthreads();
  int idx = blockIdx.x*256 + threadIdx.x;
  float mv = 0.f;
  if (idx < 2*VOL) {
    int b = idx / VOL; int vox = idx % VOL;
    int z = vox / SL; int r = vox % SL; int y = r / RW; int x = r % RW;
    const float* base = in + (size_t)b*12*VOL + (size_t)z*SL + (size_t)y*RW;
    float s[12]; float mn = 3.4e38f;
    #pragma unroll
    for (int c=0;c<12;++c) {
      const float* pc = base + (size_t)c*VOL;
      float t = 0.f;
      #pragma unroll
      for (int d=-2;d<=2;++d) { int xc = clampi(x+d,0,89); t += pc[xc]; }
      t *= (1.0f/125.0f);
      s[c] = t; mn = fminf(mn, t);
    }
    float* ob = outPre + (size_t)b*12*VOL + vox;
    #pragma unroll
    for (int c=0;c<12;++c) { float pre = s[c]-mn; ob[(size_t)c*VOL] = pre; mv += pre; }
    mv *= (1.0f/12.0f);
  }
  #pragma unroll
  for (int o=32;o;o>>=1) mv += __shfl_xor(mv, o);
  if ((threadIdx.x & 63)==0 && mv != 0.f) atomicAdd(&red, mv);
  __syncthreads();
  if (threadIdx.x==0) atomicAdd(mvsum, red);
}

__global__ void finalize_kernel(const float* __restrict__ pre, float* __restrict__ out,
                                const float* __restrict__ mvsum) {
  int idx = blockIdx.x*256 + threadIdx.x;
  if (idx >= 2*VOL) return;
  int b = idx / VOL; int vox = idx % VOL;
  const float* base = pre + (size_t)b*12*VOL + vox;
  float* ob = out + (size_t)b*12*VOL + vox;
  float s[12]; float mv = 0.f;
  #pragma unroll
  for (int c=0;c<12;++c) { s[c] = base[(size_t)c*VOL]; mv += s[c]; }
  mv *= (1.0f/12.0f);
  float mm = *mvsum * (1.0f/1458000.0f);
  float mvc = fminf(fmaxf(mv, mm*0.001f), mm*1000.0f);
  float inv = 1.0f / mvc;
  #pragma unroll
  for (int c=0;c<12;++c) ob[(size_t)c*VOL] = __expf(-s[c]*inv);
}

template<int P>
__global__ __launch_bounds__(64) void pack_kernel(const float* __restrict__ mind,
                                                  ushort* __restrict__ out) {
  constexpr int NG=90/P, N=NG*NG*NG, C=12*P*P*P;
  int d = blockIdx.x;
  int b = d / N, n = d % N;
  int gz = n/(NG*NG), rn = n%(NG*NG), gy = rn/NG, gx = rn%NG;
  const float* mf = mind + (size_t)b*12*VOL + (size_t)gz*P*SL + (size_t)gy*P*RW + gx*P;
  int lane = threadIdx.x;
  float ss = 0.f;
  for (int j = lane; j < C; j += 64) {
    int c = j/(P*P*P); int r = j%(P*P*P); int dz = r/(P*P); int r2 = r%(P*P); int dy = r2/P; int dx = r2%P;
    float v = mf[(size_t)c*VOL + dz*SL + dy*RW + dx];
    ss += v*v;
  }
  #pragma unroll
  for (int o=32;o;o>>=1) ss += __shfl_xor(ss, o);
  float inv = 1.0f/fmaxf(sqrtf(ss), 1e-12f);
  ushort* ob = out + (size_t)d*C;
  for (int j = lane; j < C; j += 64) {
    int c = j/(P*P*P); int r = j%(P*P*P); int dz = r/(P*P); int r2 = r%(P*P); int dy = r2/P; int dx = r2%P;
    float v = mf[(size_t)c*VOL + dz*SL + dy*RW + dx] * inv;
    __hip_bfloat16 h = __float2bfloat16(v);
    ob[j] = *(ushort*)&h;
  }
}

union FragU { s8v s; uint u[4]; };

__device__ __forceinline__ s8v ldfrag(const ushort* p) {
  FragU f;
  uint2 a = *(const uint2*)p;
  uint2 b = *(const uint2*)(p + 4);
  f.u[0]=a.x; f.u[1]=a.y; f.u[2]=b.x; f.u[3]=b.y;
  return f.s;
}
__device__ __forceinline__ s8v ldfrag_m(const ushort* p, bool v0, bool v1) {
  FragU f;
  if (v0) { uint2 a = *(const uint2*)p;     f.u[0]=a.x; f.u[1]=a.y; } else { f.u[0]=0; f.u[1]=0; }
  if (v1) { uint2 b = *(const uint2*)(p+4); f.u[2]=b.x; f.u[3]=b.y; } else { f.u[2]=0; f.u[3]=0; }
  return f.s;
}

// block = (b, mz-plane, gy, j), gz = mz-R+j. Plane-major + bijective XCD swizzle
// keeps both the B z-plane and the A lines of a plane-group L2-resident.
// K-segmented: per segment each wave caches its A-fragments in REGISTERS
// (af[KSTEP][NRT]); the m-loop then issues only B loads. Accumulators persist
// across segments (all indices compile-time). A and B each read once per block.
template<int P, int R, int NRT, int TPB, int KSEG, int CPW>
__global__ __launch_bounds__(TPB) void loss_kernel(
    const ushort* __restrict__ pkF, const ushort* __restrict__ pkM,
    float* __restrict__ sumG, float* __restrict__ alnG) {
  constexpr int NG=90/P, N=NG*NG*NG, C=12*P*P*P;
  constexpr int NW=TPB/64, WZ=2*R+1;
  constexpr int KSTEP=KSEG/32;
  constexpr int NSEG=(C+KSEG-1)/KSEG;
  constexpr int NROWS=NRT*16;
  static_assert(NROWS >= NG, "row tiles must cover the x line");
  static_assert((WZ*NG+15)/16 <= CPW*NW, "chunks must cover max slice");
  static_assert(KSEG % 32 == 0, "KSEG multiple of 32");
  __shared__ float sumS[NROWS];
  int nwg = gridDim.x;
  int q = nwg >> 3, r8 = nwg & 7;
  int xcd = blockIdx.x & 7, sidx = blockIdx.x >> 3;
  int lid = (xcd < r8 ? xcd*(q+1) : r8*(q+1) + (xcd - r8)*q) + sidx;
  int j = lid % WZ; int t1 = lid / WZ;
  int gy = t1 % NG; t1 /= NG;
  int mz = t1 % NG; int b = t1 / NG;
  int gz = mz - R + j;
  if (gz < 0 || gz >= NG) return;
  int tid = threadIdx.x; int lane = tid & 63; int wv = tid >> 6;
  int col = lane & 15, grp = lane >> 4;
  const int ko = grp*8;
  for (int i = tid; i < NROWS; i += TPB) sumS[i] = 0.f;
  __syncthreads();
  size_t baseF = ((size_t)b*N + ((size_t)gz*NG + gy)*NG) * C;
  const ushort* aRow[NRT];
  #pragma unroll
  for (int t=0;t<NRT;++t) {
    int row = t*16 + col; if (row > NG-1) row = NG-1;
    aRow[t] = pkF + baseF + (size_t)row*C;
  }
  int y0 = max(gy-R,0), y1 = min(gy+R,NG-1);
  int wy = y1-y0+1;
  int Ms = wy*NG;
  int nch = (Ms+15)>>4;
  const ushort* sliceM = pkM + ((size_t)b*N + ((size_t)mz*NG + y0)*NG) * C;
  float* lineSum = sumG + (size_t)b*N + ((size_t)gz*NG + gy)*NG;
  float* lineAln = alnG + (size_t)b*N + ((size_t)gz*NG + gy)*NG;

  f32x4 acc[CPW][NRT];
  #pragma unroll
  for (int ch=0;ch<CPW;++ch)
    #pragma unroll
    for (int t=0;t<NRT;++t) acc[ch][t] = (f32x4){0.f,0.f,0.f,0.f};

  for (int seg=0; seg<NSEG; ++seg) {
    int koff = seg*KSEG;
    s8v af[KSTEP][NRT];
    #pragma unroll
    for (int k=0;k<KSTEP;++k) {
      int kg = koff + k*32 + ko;
      bool full = (koff + k*32 + 32 <= C);
      #pragma unroll
      for (int t=0;t<NRT;++t)
        af[k][t] = full ? ldfrag(aRow[t] + kg) : ldfrag_m(aRow[t] + kg, kg < C, kg+4 < C);
    }
    #pragma unroll
    for (int ch=0;ch<CPW;++ch) {
      int mc = wv + ch*NW;
      if (mc < nch) {                       // wave-uniform
        int mu = mc*16 + col;
        int mus = (mu < Ms) ? mu : 0;
        const ushort* pb = sliceM + (size_t)mus*C + koff;
        #pragma unroll
        for (int k=0;k<KSTEP;++k) {
          int kg = koff + k*32 + ko;
          bool full = (koff + k*32 + 32 <= C);
          s8v bf = full ? ldfrag(pb + k*32 + ko)
                        : ldfrag_m(pb + k*32 + ko, kg < C, kg+4 < C);
          #pragma unroll
          for (int t=0;t<NRT;++t)
            acc[ch][t] = __builtin_amdgcn_mfma_f32_16x16x32_bf16(af[k][t], bf, acc[ch][t], 0,0,0);
        }
      }
    }
  }

  float sumE[NRT][4];
  #pragma unroll
  for (int t=0;t<NRT;++t) { sumE[t][0]=0.f; sumE[t][1]=0.f; sumE[t][2]=0.f; sumE[t][3]=0.f; }
  #pragma unroll
  for (int ch=0;ch<CPW;++ch) {
    int mc = wv + ch*NW;
    if (mc < nch) {
      int mu = mc*16 + col; bool vm = mu < Ms;
      int mus = vm ? mu : 0;
      int myq = mus/NG; int my = y0 + myq; int mx = mus - myq*NG;
      #pragma unroll
      for (int t=0;t<NRT;++t) {
        #pragma unroll
        for (int jj=0;jj<4;++jj) {
          int x = t*16 + grp*4 + jj;           // D row = (lane>>4)*4 + reg
          float sim = acc[ch][t][jj];
          bool ok = vm && (x < NG) && (mx - x <= R) && (x - mx <= R);
          if (ok) {
            sumE[t][jj] += __expf(sim);
            if (mz==gz && my==gy && mx==x) lineAln[x] = sim;
          }
        }
      }
    }
  }
  #pragma unroll
  for (int t=0;t<NRT;++t) {
    #pragma unroll
    for (int jj=0;jj<4;++jj) {
      float v = sumE[t][jj];
      v += __shfl_xor(v,1); v += __shfl_xor(v,2); v += __shfl_xor(v,4); v += __shfl_xor(v,8);
      if (col==0) atomicAdd(&sumS[t*16 + grp*4 + jj], v);
    }
  }
  __syncthreads();
  if (tid < NG) {
    float v = sumS[tid];
    if (v != 0.f) atomicAdd(&lineSum[tid], v);
  }
}

__global__ void epilogue_kernel(const float* __restrict__ sumG, const float* __restrict__ alnG,
                                const float* __restrict__ sw, float* __restrict__ out) {
  constexpr int N3 = 54000, N5 = 11664, N9 = 2000;
  constexpr int TOT = N3 + N5 + N9;
  __shared__ float wred[4];
  int idx = blockIdx.x*256 + threadIdx.x;
  float w0 = sw[0], w1 = sw[1], w2 = sw[2];
  float mx = fmaxf(w0, fmaxf(w1, w2));
  float e0 = __expf(w0-mx), e1 = __expf(w1-mx), e2 = __expf(w2-mx);
  float ise = 1.0f/(e0+e1+e2);
  float c = 0.f;
  if (idx < TOT) {
    float coef;
    if (idx < N3)            coef = e0*ise/(float)N3;
    else if (idx < N3+N5)    coef = e1*ise/(float)N5;
    else                     coef = e2*ise/(float)N9;
    c = (__logf(sumG[idx]) - alnG[idx]) * coef;
  }
  #pragma unroll
  for (int o=32;o;o>>=1) c += __shfl_xor(c, o);
  if ((threadIdx.x & 63)==0) wred[threadIdx.x>>6] = c;
  __syncthreads();
  if (threadIdx.x==0) {
    float s = wred[0]+wred[1]+wred[2]+wred[3];
    if (s != 0.f) atomicAdd(out, s);
  }
}

static inline int cdiv(long long a, int b) { return (int)((a + b - 1) / b); }

template<int P, int R, int NRT, int TPB, int KSEG, int CPW>
static void run_scale(const float* Yf, const float* Ym, ushort* pkF, ushort* pkM,
                      float* sumG, float* alnG, hipStream_t s) {
  constexpr int NG=90/P, N=NG*NG*NG;
  pack_kernel<P><<<2*N, 64, 0, s>>>(Yf, pkF);
  pack_kernel<P><<<2*N, 64, 0, s>>>(Ym, pkM);
  loss_kernel<P,R,NRT,TPB,KSEG,CPW><<<2*NG*NG*(2*R+1), TPB, 0, s>>>(pkF, pkM, sumG, alnG);
}

extern "C" void kernel_launch(void* const* d_in, const int* in_sizes, int n_in,
                              void* d_out, int out_size, void* d_ws, size_t ws_size,
                              hipStream_t stream) {
  const float* fixedI  = (const float*)d_in[0];
  const float* movingI = (const float*)d_in[1];
  const float* scale_w = (const float*)d_in[2];
  float* out = (float*)d_out;

  uint8_t* w = (uint8_t*)d_ws;
  float*  smallb = (float*)w;                    // [0]=mv_f [1]=mv_m
  float*  sumG = (float*)(w + 4096);
  float*  alnG = sumG + 67664;
  ushort* PK  = (ushort*)(w + (1u<<20));
  float*  X   = (float*)(w + (1u<<20));          // alias of PK
  float*  Yf  = (float*)(w + (1u<<20) + 69984000);
  float*  Ym  = Yf + 17496000;
  ushort* pkF = PK;
  ushort* pkM = PK + 17496000;

  hipMemsetAsync(w, 0, 4096 + 67664*4, stream);  // smallb + sumG (alnG always overwritten)
  hipMemsetAsync(d_out, 0, sizeof(float), stream);

  const int gE = cdiv(17496000, 256);
  const int gV = cdiv(1458000, 256);

  diff2z_kernel<<<gE,256,0,stream>>>(fixedI, X);
  boxy_kernel<<<gE,256,0,stream>>>(X, Yf);
  boxxmin_kernel<<<gV,256,0,stream>>>(Yf, X, smallb+0);
  finalize_kernel<<<gV,256,0,stream>>>(X, Yf, smallb+0);

  diff2z_kernel<<<gE,256,0,stream>>>(movingI, X);
  boxy_kernel<<<gE,256,0,stream>>>(X, Ym);
  boxxmin_kernel<<<gV,256,0,stream>>>(Ym, X, smallb+1);
  finalize_kernel<<<gV,256,0,stream>>>(X, Ym, smallb+1);

  // P=3: C=324, 1 seg of 352 (af 88 VGPR); P=5: C=1500, 6x256; P=9: C=8748, 35x256
  run_scale<3,3,2,256,352,4>(Yf, Ym, pkF, pkM, sumG,         alnG,         stream);
  run_scale<5,2,2,256,256,2>(Yf, Ym, pkF, pkM, sumG + 54000, alnG + 54000, stream);
  run_scale<9,1,1,128,256,1>(Yf, Ym, pkF, pkM, sumG + 65664, alnG + 65664, stream);

  epilogue_kernel<<<cdiv(67664,256),256,0,stream>>>(sumG, alnG, scale_w, out);
}

// Round 6
// 1612.700 us; speedup vs baseline: 3.3775x; 1.0124x over previous
//
#include <hip/hip_runtime.h>
#include <hip/hip_bf16.h>
#include <math.h>

#define VOL 729000
#define SL  8100
#define RW  90

typedef __attribute__((ext_vector_type(8))) short s8v;
typedef __attribute__((ext_vector_type(4))) float f32x4;

__device__ __constant__ int c_o1[12][3] = {
  {0,0,-2},{0,-2,0},{0,-2,0},{0,0,2},{0,0,2},{2,0,0},{2,0,0},{2,0,0},{0,2,0},{0,2,0},{0,2,0},{0,2,0}
};
__device__ __constant__ int c_o2[12][3] = {
  {-2,0,0},{-2,0,0},{0,0,-2},{-2,0,0},{0,-2,0},{0,0,-2},{0,-2,0},{0,0,2},{-2,0,0},{0,0,-2},{0,0,2},{2,0,0}
};

__device__ __forceinline__ int clampi(int v, int lo, int hi){ return v<lo?lo:(v>hi?hi:v); }

typedef __attribute__((address_space(3))) uint lds_uint;
typedef __attribute__((address_space(1))) uint glb_uint;
__device__ __forceinline__ void gl_lds16(const ushort* g, ushort* l) {
  // per-lane global src gather; LDS dst = wave-uniform base + lane*16B
  __builtin_amdgcn_global_load_lds((const glb_uint*)g, (lds_uint*)l, 16, 0, 0);
}

__global__ void diff2z_kernel(const float* __restrict__ img, float* __restrict__ out) {
  int idx = blockIdx.x*256 + threadIdx.x;
  if (idx >= 2*12*VOL) return;
  int vox = idx % VOL; int ct = idx / VOL; int t = ct % 12, b = ct / 12;
  int z = vox / SL; int r = vox % SL; int y = r / RW; int x = r % RW;
  const float* im = img + (size_t)b*VOL;
  int o1z=c_o1[t][0], o1y=c_o1[t][1], o1x=c_o1[t][2];
  int o2z=c_o2[t][0], o2y=c_o2[t][1], o2x=c_o2[t][2];
  int y1 = clampi(y+o1y,0,89), x1 = clampi(x+o1x,0,89);
  int y2 = clampi(y+o2y,0,89), x2 = clampi(x+o2x,0,89);
  float s = 0.f;
  #pragma unroll
  for (int d=-2; d<=2; ++d) {
    int zz = clampi(z+d,0,89);
    int z1 = clampi(zz+o1z,0,89), z2 = clampi(zz+o2z,0,89);
    float dv = im[z1*SL+y1*RW+x1] - im[z2*SL+y2*RW+x2];
    s += dv*dv;
  }
  out[idx] = s;
}

__global__ void boxy_kernel(const float* __restrict__ in, float* __restrict__ out) {
  int idx = blockIdx.x*256 + threadIdx.x;
  if (idx >= 2*12*VOL) return;
  int vox = idx % VOL; int bc = idx / VOL;
  int z = vox / SL; int r = vox % SL; int y = r / RW; int x = r % RW;
  const float* p = in + (size_t)bc*VOL + (size_t)z*SL + x;
  float s = 0.f;
  #pragma unroll
  for (int d=-2; d<=2; ++d) { int yc = clampi(y+d,0,89); s += p[yc*RW]; }
  out[idx] = s;
}

__global__ void boxxmin_kernel(const float* __restrict__ in, float* __restrict__ outPre,
                               float* __restrict__ mvsum) {
  __shared__ float red;
  if (threadIdx.x == 0) red = 0.f;
  __syncthreads();
  int idx = blockIdx.x*256 + threadIdx.x;
  float mv = 0.f;
  if (idx < 2*VOL) {
    int b = idx / VOL; int vox = idx % VOL;
    int z = vox / SL; int r = vox % SL; int y = r / RW; int x = r % RW;
    const float* base = in + (size_t)b*12*VOL + (size_t)z*SL + (size_t)y*RW;
    float s[12]; float mn = 3.4e38f;
    #pragma unroll
    for (int c=0;c<12;++c) {
      const float* pc = base + (size_t)c*VOL;
      float t = 0.f;
      #pragma unroll
      for (int d=-2;d<=2;++d) { int xc = clampi(x+d,0,89); t += pc[xc]; }
      t *= (1.0f/125.0f);
      s[c] = t; mn = fminf(mn, t);
    }
    float* ob = outPre + (size_t)b*12*VOL + vox;
    #pragma unroll
    for (int c=0;c<12;++c) { float pre = s[c]-mn; ob[(size_t)c*VOL] = pre; mv += pre; }
    mv *= (1.0f/12.0f);
  }
  #pragma unroll
  for (int o=32;o;o>>=1) mv += __shfl_xor(mv, o);
  if ((threadIdx.x & 63)==0 && mv != 0.f) atomicAdd(&red, mv);
  __syncthreads();
  if (threadIdx.x==0) atomicAdd(mvsum, red);
}

__global__ void finalize_kernel(const float* __restrict__ pre, float* __restrict__ out,
                                const float* __restrict__ mvsum) {
  int idx = blockIdx.x*256 + threadIdx.x;
  if (idx >= 2*VOL) return;
  int b = idx / VOL; int vox = idx % VOL;
  const float* base = pre + (size_t)b*12*VOL + vox;
  float* ob = out + (size_t)b*12*VOL + vox;
  float s[12]; float mv = 0.f;
  #pragma unroll
  for (int c=0;c<12;++c) { s[c] = base[(size_t)c*VOL]; mv += s[c]; }
  mv *= (1.0f/12.0f);
  float mm = *mvsum * (1.0f/1458000.0f);
  float mvc = fminf(fmaxf(mv, mm*0.001f), mm*1000.0f);
  float inv = 1.0f / mvc;
  #pragma unroll
  for (int c=0;c<12;++c) ob[(size_t)c*VOL] = __expf(-s[c]*inv);
}

template<int P>
__global__ __launch_bounds__(64) void pack_kernel(const float* __restrict__ mind,
                                                  ushort* __restrict__ out) {
  constexpr int NG=90/P, N=NG*NG*NG, C=12*P*P*P;
  int d = blockIdx.x;
  int b = d / N, n = d % N;
  int gz = n/(NG*NG), rn = n%(NG*NG), gy = rn/NG, gx = rn%NG;
  const float* mf = mind + (size_t)b*12*VOL + (size_t)gz*P*SL + (size_t)gy*P*RW + gx*P;
  int lane = threadIdx.x;
  float ss = 0.f;
  for (int j = lane; j < C; j += 64) {
    int c = j/(P*P*P); int r = j%(P*P*P); int dz = r/(P*P); int r2 = r%(P*P); int dy = r2/P; int dx = r2%P;
    float v = mf[(size_t)c*VOL + dz*SL + dy*RW + dx];
    ss += v*v;
  }
  #pragma unroll
  for (int o=32;o;o>>=1) ss += __shfl_xor(ss, o);
  float inv = 1.0f/fmaxf(sqrtf(ss), 1e-12f);
  ushort* ob = out + (size_t)d*C;
  for (int j = lane; j < C; j += 64) {
    int c = j/(P*P*P); int r = j%(P*P*P); int dz = r/(P*P); int r2 = r%(P*P); int dy = r2/P; int dx = r2%P;
    float v = mf[(size_t)c*VOL + dz*SL + dy*RW + dx] * inv;
    __hip_bfloat16 h = __float2bfloat16(v);
    ob[j] = *(ushort*)&h;
  }
}

union FragU { s8v s; uint u[4]; };
__device__ __forceinline__ s8v ldfrag_m(const ushort* p, bool v0, bool v1) {
  FragU f;
  if (v0) { uint2 a = *(const uint2*)p;     f.u[0]=a.x; f.u[1]=a.y; } else { f.u[0]=0; f.u[1]=0; }
  if (v1) { uint2 b = *(const uint2*)(p+4); f.u[2]=b.x; f.u[3]=b.y; } else { f.u[2]=0; f.u[3]=0; }
  return f.s;
}

// Frag-native LDS GEMM loss. Block = (b, mz, gy, j), gz = mz-R+j (plane-major +
// bijective XCD swizzle). K in kb-phases of 128 elems, double-buffered: each
// phase stages A-tiles (per-kb, or full-resident for AFULL) and each wave's
// B-chunk tiles via global_load_lds with per-lane gathered src so that LDS
// layout == MFMA fragment order: every fragment is one linear conflict-free
// ds_read_b128. Rounds (outer) sweep m-chunks; K-tail (C%32) via one masked
// scattered MFMA per chunk.
template<int P, int R, int NRT, int TPB, bool AFULL>
__global__ __launch_bounds__(TPB) void loss_kernel(
    const ushort* __restrict__ pkF, const ushort* __restrict__ pkM,
    float* __restrict__ sumG, float* __restrict__ alnG) {
  constexpr int NG=90/P, N=NG*NG*NG, C=12*P*P*P;
  constexpr int NW=TPB/64, WZ=2*R+1;
  constexpr int KMAIN = C & ~31;            // 320 / 1472 / 8736
  constexpr int NKB = (KMAIN + 127)/128;
  constexpr int NROWS = NRT*16;
  constexpr int ATILES = AFULL ? 0 : 4*NRT; // per-phase A tiles
  constexpr int PHTILES = ATILES + NW*4;
  constexpr int AFT = AFULL ? (KMAIN/32)*NRT : 1;
  static_assert(NROWS >= NG, "rows cover x line");
  __shared__ float sumS[NROWS];
  __shared__ __align__(16) ushort aT[AFT*512];
  __shared__ __align__(16) ushort bP[2][PHTILES*512];

  int nwg = gridDim.x;
  int q = nwg >> 3, r8 = nwg & 7;
  int xcd = blockIdx.x & 7, sidx = blockIdx.x >> 3;
  int lid = (xcd < r8 ? xcd*(q+1) : r8*(q+1) + (xcd - r8)*q) + sidx;
  int j = lid % WZ; int t1 = lid / WZ;
  int gy = t1 % NG; t1 /= NG;
  int mz = t1 % NG; int b = t1 / NG;
  int gz = mz - R + j;
  if (gz < 0 || gz >= NG) return;
  int tid = threadIdx.x; int lane = tid & 63; int wv = tid >> 6;
  int col = lane & 15, grp = lane >> 4;
  const int ko = grp*8;
  for (int i = tid; i < NROWS; i += TPB) sumS[i] = 0.f;

  size_t baseF = ((size_t)b*N + ((size_t)gz*NG + gy)*NG) * C;
  const ushort* aRow[NRT];
  #pragma unroll
  for (int t=0;t<NRT;++t) {
    int row = t*16 + col; if (row > NG-1) row = NG-1;
    aRow[t] = pkF + baseF + (size_t)row*C;
  }
  int y0 = max(gy-R,0), y1 = min(gy+R,NG-1);
  int wy = y1-y0+1;
  int Ms = wy*NG;
  int nch = (Ms+15)>>4;
  const ushort* sliceM = pkM + ((size_t)b*N + ((size_t)mz*NG + y0)*NG) * C;
  float* lineSum = sumG + (size_t)b*N + ((size_t)gz*NG + gy)*NG;
  float* lineAln = alnG + (size_t)b*N + ((size_t)gz*NG + gy)*NG;

  int NR = (nch + NW - 1)/NW;
  int NP = NR*NKB;

  auto stageA = [&](int kb, ushort* dst) {
    int k4cnt = min(4, (KMAIN - kb*128) >> 5);
    for (int i = wv; i < 4*NRT; i += NW) {
      int k4 = i/NRT, t = i - k4*NRT;
      if (k4 < k4cnt)
        gl_lds16(aRow[t] + kb*128 + k4*32 + ko, dst + i*512);
    }
  };
  auto stageB = [&](int r, int kb, ushort* dstB) {
    int k4cnt = min(4, (KMAIN - kb*128) >> 5);
    int chunk = r*NW + wv;
    if (chunk < nch) {
      int descIdx = chunk*16 + col;
      int desc = min(descIdx, Ms-1);
      const ushort* srcD = sliceM + (size_t)desc*C + kb*128 + ko;
      for (int k4 = 0; k4 < k4cnt; ++k4)
        gl_lds16(srcD + k4*32, dstB + (wv*4 + k4)*512);
    }
  };

  // prologue
  if constexpr (AFULL) {
    for (int i = wv; i < (KMAIN/32)*NRT; i += NW) {
      int ak4 = i/NRT, t = i - ak4*NRT;
      gl_lds16(aRow[t] + ak4*32 + ko, aT + i*512);
    }
  } else {
    stageA(0, bP[0]);
  }
  stageB(0, 0, bP[0] + ATILES*512);
  __syncthreads();

  float sumE[NRT][4];
  f32x4 acc[NRT];
  #pragma unroll
  for (int t=0;t<NRT;++t) {
    acc[t] = (f32x4){0.f,0.f,0.f,0.f};
    #pragma unroll
    for (int jj=0;jj<4;++jj) sumE[t][jj] = 0.f;
  }

  int buf = 0;
  for (int p = 0; p < NP; ++p) {
    int r = p/NKB, kb = p - r*NKB;
    int pn = p + 1;
    if (pn < NP) {
      int rn = pn/NKB, kbn = pn - rn*NKB;
      if constexpr (!AFULL) stageA(kbn, bP[buf^1]);
      stageB(rn, kbn, bP[buf^1] + ATILES*512);
    }
    int k4cnt = min(4, (KMAIN - kb*128) >> 5);
    int chunk = r*NW + wv;
    if (chunk < nch) {
      const ushort* bbase = bP[buf] + (ATILES + wv*4)*512 + lane*8;
      for (int k4 = 0; k4 < k4cnt; ++k4) {
        s8v bf = *(const s8v*)(bbase + k4*512);
        #pragma unroll
        for (int t=0;t<NRT;++t) {
          const ushort* ap;
          if constexpr (AFULL) ap = aT + (((kb*4 + k4)*NRT) + t)*512 + lane*8;
          else                 ap = bP[buf] + (k4*NRT + t)*512 + lane*8;
          s8v af = *(const s8v*)ap;
          acc[t] = __builtin_amdgcn_mfma_f32_16x16x32_bf16(af, bf, acc[t], 0,0,0);
        }
      }
      if (kb == NKB-1) {
        // K-tail (C % 32 elems) via masked scattered frags
        int mu = chunk*16 + col; bool vm = mu < Ms;
        int mus = vm ? mu : 0;
        const ushort* pb = sliceM + (size_t)mus*C;
        int kg = KMAIN + ko;
        bool v0 = (kg+4 <= C), v1 = (kg+8 <= C);
        if constexpr ((C & 31) != 0) {
          s8v bft = ldfrag_m(pb + kg, v0, v1);
          #pragma unroll
          for (int t=0;t<NRT;++t) {
            s8v aft = ldfrag_m(aRow[t] + kg, v0, v1);
            acc[t] = __builtin_amdgcn_mfma_f32_16x16x32_bf16(aft, bft, acc[t], 0,0,0);
          }
        }
        // round epilogue
        int myq = mus/NG; int my = y0 + myq; int mx = mus - myq*NG;
        #pragma unroll
        for (int t=0;t<NRT;++t) {
          #pragma unroll
          for (int jj=0;jj<4;++jj) {
            int x = t*16 + grp*4 + jj;
            float sim = acc[t][jj];
            bool ok = vm && (x < NG) && (mx - x <= R) && (x - mx <= R);
            if (ok) {
              sumE[t][jj] += __expf(sim);
              if (mz==gz && my==gy && mx==x) lineAln[x] = sim;
            }
          }
          acc[t] = (f32x4){0.f,0.f,0.f,0.f};
        }
      }
    }
    __syncthreads();
    buf ^= 1;
  }

  #pragma unroll
  for (int t=0;t<NRT;++t) {
    #pragma unroll
    for (int jj=0;jj<4;++jj) {
      float v = sumE[t][jj];
      v += __shfl_xor(v,1); v += __shfl_xor(v,2); v += __shfl_xor(v,4); v += __shfl_xor(v,8);
      if (col==0) atomicAdd(&sumS[t*16 + grp*4 + jj], v);
    }
  }
  __syncthreads();
  if (tid < NG) {
    float v = sumS[tid];
    if (v != 0.f) atomicAdd(&lineSum[tid], v);
  }
}

__global__ void epilogue_kernel(const float* __restrict__ sumG, const float* __restrict__ alnG,
                                const float* __restrict__ sw, float* __restrict__ out) {
  constexpr int N3 = 54000, N5 = 11664, N9 = 2000;
  constexpr int TOT = N3 + N5 + N9;
  __shared__ float wred[4];
  int idx = blockIdx.x*256 + threadIdx.x;
  float w0 = sw[0], w1 = sw[1], w2 = sw[2];
  float mx = fmaxf(w0, fmaxf(w1, w2));
  float e0 = __expf(w0-mx), e1 = __expf(w1-mx), e2 = __expf(w2-mx);
  float ise = 1.0f/(e0+e1+e2);
  float c = 0.f;
  if (idx < TOT) {
    float coef;
    if (idx < N3)            coef = e0*ise/(float)N3;
    else if (idx < N3+N5)    coef = e1*ise/(float)N5;
    else                     coef = e2*ise/(float)N9;
    c = (__logf(sumG[idx]) - alnG[idx]) * coef;
  }
  #pragma unroll
  for (int o=32;o;o>>=1) c += __shfl_xor(c, o);
  if ((threadIdx.x & 63)==0) wred[threadIdx.x>>6] = c;
  __syncthreads();
  if (threadIdx.x==0) {
    float s = wred[0]+wred[1]+wred[2]+wred[3];
    if (s != 0.f) atomicAdd(out, s);
  }
}

static inline int cdiv(long long a, int b) { return (int)((a + b - 1) / b); }

template<int P, int R, int NRT, int TPB, bool AFULL>
static void run_scale(const float* Yf, const float* Ym, ushort* pkF, ushort* pkM,
                      float* sumG, float* alnG, hipStream_t s) {
  constexpr int NG=90/P, N=NG*NG*NG;
  pack_kernel<P><<<2*N, 64, 0, s>>>(Yf, pkF);
  pack_kernel<P><<<2*N, 64, 0, s>>>(Ym, pkM);
  loss_kernel<P,R,NRT,TPB,AFULL><<<2*NG*NG*(2*R+1), TPB, 0, s>>>(pkF, pkM, sumG, alnG);
}

extern "C" void kernel_launch(void* const* d_in, const int* in_sizes, int n_in,
                              void* d_out, int out_size, void* d_ws, size_t ws_size,
                              hipStream_t stream) {
  const float* fixedI  = (const float*)d_in[0];
  const float* movingI = (const float*)d_in[1];
  const float* scale_w = (const float*)d_in[2];
  float* out = (float*)d_out;

  uint8_t* w = (uint8_t*)d_ws;
  float*  smallb = (float*)w;                    // [0]=mv_f [1]=mv_m
  float*  sumG = (float*)(w + 4096);
  float*  alnG = sumG + 67664;
  ushort* PK  = (ushort*)(w + (1u<<20));
  float*  X   = (float*)(w + (1u<<20));          // alias of PK
  float*  Yf  = (float*)(w + (1u<<20) + 69984000);
  float*  Ym  = Yf + 17496000;
  ushort* pkF = PK;
  ushort* pkM = PK + 17496000;

  hipMemsetAsync(w, 0, 4096 + 67664*4, stream);  // smallb + sumG (alnG always overwritten)
  hipMemsetAsync(d_out, 0, sizeof(float), stream);

  const int gE = cdiv(17496000, 256);
  const int gV = cdiv(1458000, 256);

  diff2z_kernel<<<gE,256,0,stream>>>(fixedI, X);
  boxy_kernel<<<gE,256,0,stream>>>(X, Yf);
  boxxmin_kernel<<<gV,256,0,stream>>>(Yf, X, smallb+0);
  finalize_kernel<<<gV,256,0,stream>>>(X, Yf, smallb+0);

  diff2z_kernel<<<gE,256,0,stream>>>(movingI, X);
  boxy_kernel<<<gE,256,0,stream>>>(X, Ym);
  boxxmin_kernel<<<gV,256,0,stream>>>(Ym, X, smallb+1);
  finalize_kernel<<<gV,256,0,stream>>>(X, Ym, smallb+1);

  // P3: A frag-resident (20KB) + B dbuf 32KB; P5/P9: per-phase A+B dbuf
  run_scale<3,3,2,256,true >(Yf, Ym, pkF, pkM, sumG,         alnG,         stream);
  run_scale<5,2,2,256,false>(Yf, Ym, pkF, pkM, sumG + 54000, alnG + 54000, stream);
  run_scale<9,1,1,128,false>(Yf, Ym, pkF, pkM, sumG + 65664, alnG + 65664, stream);

  epilogue_kernel<<<cdiv(67664,256),256,0,stream>>>(sumG, alnG, scale_w, out);
}